// Round 1
// baseline (208.031 us; speedup 1.0000x reference)
//
#include <hip/hip_runtime.h>

// YOLO loss: pred (16384, 30, 7, 7) f32, target (16384, 7, 7, 25) f32 -> scalar f32.
// pred reshape (B,7,7,30) is a pure reinterpret: each cell = 30 consecutive floats.
// One thread per cell; 256 cells/block; LDS staging for coalesced global loads.

#define NCLS 20
#define CELLS_PER_BLOCK 256
#define PRED_PER_CELL 30
#define TGT_PER_CELL 25
#define NUM_BLOCKS 3136   // 16384*49 / 256

__global__ __launch_bounds__(256) void yolo_loss_kernel(
    const float* __restrict__ pred,
    const float* __restrict__ target,
    float* __restrict__ out)
{
    __shared__ float sp[CELLS_PER_BLOCK * PRED_PER_CELL]; // 30720 B
    __shared__ float st[CELLS_PER_BLOCK * TGT_PER_CELL];  // 25600 B
    __shared__ float wave_sums[4];

    const int tid = threadIdx.x;
    const long long blk = blockIdx.x;

    // ---- Stage pred slice: 7680 floats = 1920 float4 (base 16B-aligned: blk*30720B)
    {
        const float4* g = (const float4*)(pred + blk * (CELLS_PER_BLOCK * PRED_PER_CELL));
        float4* s = (float4*)sp;
        #pragma unroll
        for (int i = 0; i < 8; ++i) {
            int idx = tid + i * 256;
            if (idx < 1920) s[idx] = g[idx];
        }
    }
    // ---- Stage target slice: 6400 floats = 1600 float4 (base 16B-aligned: blk*25600B)
    {
        const float4* g = (const float4*)(target + blk * (CELLS_PER_BLOCK * TGT_PER_CELL));
        float4* s = (float4*)st;
        #pragma unroll
        for (int i = 0; i < 7; ++i) {
            int idx = tid + i * 256;
            if (idx < 1600) s[idx] = g[idx];
        }
    }
    __syncthreads();

    const float* lp = sp + tid * PRED_PER_CELL;
    const float* lt = st + tid * TGT_PER_CELL;

    const float EPS = 1e-6f;

    // target cell values
    const float tobj = lt[20];          // obj == p_t
    const float tx = lt[21], ty = lt[22], tw = lt[23], th = lt[24];

    // tbox corners (computed like the reference, via +/- half-extent)
    const float t_x1 = tx - tw * 0.5f, t_x2 = tx + tw * 0.5f;
    const float t_y1 = ty - th * 0.5f, t_y2 = ty + th * 0.5f;
    const float t_area = fabsf((t_x2 - t_x1) * (t_y2 - t_y1));

    // IoU for both predicted boxes
    float iou[2];
    #pragma unroll
    for (int b = 0; b < 2; ++b) {
        const float bx = lp[NCLS + 5 * b + 1];
        const float by = lp[NCLS + 5 * b + 2];
        const float bw = lp[NCLS + 5 * b + 3];
        const float bh = lp[NCLS + 5 * b + 4];
        const float x1 = bx - bw * 0.5f, x2 = bx + bw * 0.5f;
        const float y1 = by - bh * 0.5f, y2 = by + bh * 0.5f;
        const float iw = fmaxf(fminf(x2, t_x2) - fmaxf(x1, t_x1), 0.0f);
        const float ih = fmaxf(fminf(y2, t_y2) - fmaxf(y1, t_y1), 0.0f);
        const float inter = iw * ih;
        const float a1 = fabsf((x2 - x1) * (y2 - y1));
        iou[b] = inter / (a1 + t_area - inter + EPS);
    }
    // jnp.argmax: first max on ties -> strictly-greater test
    const int best = (iou[1] > iou[0]) ? 1 : 0;

    const float bconf = lp[NCLS + 5 * best + 0];
    const float bxv   = lp[NCLS + 5 * best + 1];
    const float byv   = lp[NCLS + 5 * best + 2];
    const float bwv   = lp[NCLS + 5 * best + 3];
    const float bhv   = lp[NCLS + 5 * best + 4];

    // wh = sign(wh) * sqrt(|wh| + EPS)
    const float sgnw = (bwv > 0.f) ? 1.f : ((bwv < 0.f) ? -1.f : 0.f);
    const float sgnh = (bhv > 0.f) ? 1.f : ((bhv < 0.f) ? -1.f : 0.f);
    const float swv = sgnw * sqrtf(fabsf(bwv) + EPS);
    const float shv = sgnh * sqrtf(fabsf(bhv) + EPS);

    // box loss: (obj*[x,y,sw,sh] - [obj*tx, obj*ty, sqrt(obj*tw), sqrt(obj*th)])^2
    float d0 = tobj * bxv - tobj * tx;
    float d1 = tobj * byv - tobj * ty;
    float d2 = tobj * swv - sqrtf(fmaxf(tobj * tw, 0.0f));
    float d3 = tobj * shv - sqrtf(fmaxf(tobj * th, 0.0f));
    float box_loss = d0 * d0 + d1 * d1 + d2 * d2 + d3 * d3;

    // no-object loss: both confidences
    const float noobj = 1.0f - tobj;
    float n0 = noobj * (lp[NCLS + 0] - tobj);
    float n1 = noobj * (lp[NCLS + 5] - tobj);
    float no_object_loss = n0 * n0 + n1 * n1;

    // object loss
    float od = tobj * (bconf - tobj);
    float object_loss = od * od;

    // class loss
    float class_loss = 0.0f;
    #pragma unroll
    for (int k = 0; k < NCLS; ++k) {
        float cd = tobj * (lp[k] - lt[k]);
        class_loss += cd * cd;
    }

    float loss = 5.0f * box_loss + object_loss + 0.5f * no_object_loss + class_loss;

    // ---- reduce: wave(64) shuffle -> cross-wave LDS -> one atomic per block
    #pragma unroll
    for (int off = 32; off > 0; off >>= 1)
        loss += __shfl_down(loss, off, 64);

    const int wave = tid >> 6;
    const int lane = tid & 63;
    if (lane == 0) wave_sums[wave] = loss;
    __syncthreads();
    if (tid == 0) {
        float s = wave_sums[0] + wave_sums[1] + wave_sums[2] + wave_sums[3];
        atomicAdd(out, s);
    }
}

extern "C" void kernel_launch(void* const* d_in, const int* in_sizes, int n_in,
                              void* d_out, int out_size, void* d_ws, size_t ws_size,
                              hipStream_t stream) {
    const float* pred   = (const float*)d_in[0];
    const float* target = (const float*)d_in[1];
    float* out = (float*)d_out;

    // d_out is poisoned before each launch; zero it (memset is graph-capture safe)
    hipMemsetAsync(out, 0, sizeof(float), stream);

    hipLaunchKernelGGL(yolo_loss_kernel, dim3(NUM_BLOCKS), dim3(256), 0, stream,
                       pred, target, out);
}

// Round 2
// 196.787 us; speedup vs baseline: 1.0571x; 1.0571x over previous
//
#include <hip/hip_runtime.h>
#include <stdint.h>

// YOLO loss, latency-optimized rewrite:
//  - 1-wave (64-thread) blocks, one cell per lane, 12544 blocks.
//  - global_load_lds width=16 async staging (no VGPR roundtrip, no barrier).
//  - wave-private s_waitcnt(0) instead of __syncthreads (zero barriers).
//  - LDS 14080 B/block -> ~11 blocks/CU resident (vs 2 before).
//  - wave shuffle reduce -> atomicAdd into 128 spread ws slots -> tiny reducer.

#define NCLS 20
#define SLOTS 128
#define MAIN_BLOCKS 12544   // 16384*49 / 64

__device__ static inline void load_lds16(const float* g, float* l) {
    __builtin_amdgcn_global_load_lds(
        (const __attribute__((address_space(1))) void*)g,
        (__attribute__((address_space(3))) void*)l,
        16, 0, 0);
}

__global__ __launch_bounds__(64) void yolo_main(
    const float* __restrict__ pred,
    const float* __restrict__ target,
    float* __restrict__ ws)
{
    __shared__ float sp[64 * 30];  // 7680 B, wave-private
    __shared__ float st[64 * 25];  // 6400 B

    const int lane = threadIdx.x;          // 0..63
    const int blk  = blockIdx.x;

    const float* gp = pred   + (size_t)blk * (64 * 30);
    const float* gt = target + (size_t)blk * (64 * 25);

    // ---- async stage pred: 1920 floats = 480 float4 = 7.5 rounds of 64 lanes
    #pragma unroll
    for (int r = 0; r < 7; ++r)
        load_lds16(gp + r * 256 + lane * 4, sp + r * 256);
    if (lane < 32)
        load_lds16(gp + 7 * 256 + lane * 4, sp + 7 * 256);

    // ---- async stage target: 1600 floats = 400 float4 = 6.25 rounds
    #pragma unroll
    for (int r = 0; r < 6; ++r)
        load_lds16(gt + r * 256 + lane * 4, st + r * 256);
    if (lane < 16)
        load_lds16(gt + 6 * 256 + lane * 4, st + 6 * 256);

    // wave-private drain: no __syncthreads anywhere in this kernel
    __builtin_amdgcn_s_waitcnt(0);
    __asm__ volatile("" ::: "memory");

    const float* lp = sp + lane * 30;
    const float* lt = st + lane * 25;

    const float EPS = 1e-6f;

    const float tobj = lt[20];
    const float tx = lt[21], ty = lt[22], tw = lt[23], th = lt[24];

    const float t_x1 = tx - tw * 0.5f, t_x2 = tx + tw * 0.5f;
    const float t_y1 = ty - th * 0.5f, t_y2 = ty + th * 0.5f;
    const float t_area = fabsf((t_x2 - t_x1) * (t_y2 - t_y1));

    float iou[2];
    #pragma unroll
    for (int b = 0; b < 2; ++b) {
        const float bx = lp[NCLS + 5 * b + 1];
        const float by = lp[NCLS + 5 * b + 2];
        const float bw = lp[NCLS + 5 * b + 3];
        const float bh = lp[NCLS + 5 * b + 4];
        const float x1 = bx - bw * 0.5f, x2 = bx + bw * 0.5f;
        const float y1 = by - bh * 0.5f, y2 = by + bh * 0.5f;
        const float iw = fmaxf(fminf(x2, t_x2) - fmaxf(x1, t_x1), 0.0f);
        const float ih = fmaxf(fminf(y2, t_y2) - fmaxf(y1, t_y1), 0.0f);
        const float inter = iw * ih;
        const float a1 = fabsf((x2 - x1) * (y2 - y1));
        iou[b] = inter / (a1 + t_area - inter + EPS);
    }
    const int best = (iou[1] > iou[0]) ? 1 : 0;

    const float bconf = lp[NCLS + 5 * best + 0];
    const float bxv   = lp[NCLS + 5 * best + 1];
    const float byv   = lp[NCLS + 5 * best + 2];
    const float bwv   = lp[NCLS + 5 * best + 3];
    const float bhv   = lp[NCLS + 5 * best + 4];

    const float sgnw = (bwv > 0.f) ? 1.f : ((bwv < 0.f) ? -1.f : 0.f);
    const float sgnh = (bhv > 0.f) ? 1.f : ((bhv < 0.f) ? -1.f : 0.f);
    const float swv = sgnw * sqrtf(fabsf(bwv) + EPS);
    const float shv = sgnh * sqrtf(fabsf(bhv) + EPS);

    float d0 = tobj * bxv - tobj * tx;
    float d1 = tobj * byv - tobj * ty;
    float d2 = tobj * swv - sqrtf(fmaxf(tobj * tw, 0.0f));
    float d3 = tobj * shv - sqrtf(fmaxf(tobj * th, 0.0f));
    float box_loss = d0 * d0 + d1 * d1 + d2 * d2 + d3 * d3;

    const float noobj = 1.0f - tobj;
    float n0 = noobj * (lp[NCLS + 0] - tobj);
    float n1 = noobj * (lp[NCLS + 5] - tobj);
    float no_object_loss = n0 * n0 + n1 * n1;

    float od = tobj * (bconf - tobj);
    float object_loss = od * od;

    float class_loss = 0.0f;
    #pragma unroll
    for (int k = 0; k < NCLS; ++k) {
        float cd = tobj * (lp[k] - lt[k]);
        class_loss += cd * cd;
    }

    float loss = 5.0f * box_loss + object_loss + 0.5f * no_object_loss + class_loss;

    // wave shuffle reduce (64 lanes), then one atomic per wave into a spread slot
    #pragma unroll
    for (int off = 32; off > 0; off >>= 1)
        loss += __shfl_down(loss, off, 64);

    if (lane == 0)
        atomicAdd(&ws[blk & (SLOTS - 1)], loss);
}

__global__ __launch_bounds__(64) void yolo_reduce(
    const float* __restrict__ ws, float* __restrict__ out)
{
    const int lane = threadIdx.x;
    float s = ws[lane] + ws[lane + 64];
    #pragma unroll
    for (int off = 32; off > 0; off >>= 1)
        s += __shfl_down(s, off, 64);
    if (lane == 0) out[0] = s;
}

extern "C" void kernel_launch(void* const* d_in, const int* in_sizes, int n_in,
                              void* d_out, int out_size, void* d_ws, size_t ws_size,
                              hipStream_t stream) {
    const float* pred   = (const float*)d_in[0];
    const float* target = (const float*)d_in[1];
    float* ws  = (float*)d_ws;
    float* out = (float*)d_out;

    // ws is poisoned before each launch; zero the 128 accumulation slots
    hipMemsetAsync(ws, 0, SLOTS * sizeof(float), stream);

    hipLaunchKernelGGL(yolo_main, dim3(MAIN_BLOCKS), dim3(64), 0, stream,
                       pred, target, ws);
    hipLaunchKernelGGL(yolo_reduce, dim3(1), dim3(64), 0, stream, ws, out);
}

// Round 3
// 193.327 us; speedup vs baseline: 1.0761x; 1.0179x over previous
//
#include <hip/hip_runtime.h>
#include <stdint.h>

// YOLO loss R3: persistent 1-wave blocks + double-buffered async LDS staging
// with fine-grained vmcnt waits (never drain to 0 mid-loop, no barriers).
//  - 1280 blocks x 64 threads (5 blocks/CU at 28 KB LDS), grid-stride over
//    12544 tiles (~10 tiles/wave) -> no workgroup churn, loads always in flight.
//  - stage(t+1) issued BEFORE waiting on tile t: s_waitcnt vmcnt(15) keeps
//    the next tile's 15 loads outstanding while computing tile t.

#define NCLS 20
#define SLOTS 128
#define GRID 1280
#define TILES 12544          // 16384*49 / 64 cells per tile

// s_waitcnt imm: [3:0]=vmcnt lo, [6:4]=expcnt, [11:8]=lgkmcnt, [15:14]=vmcnt hi
#define WAIT_VM15 0x0F7F     // vmcnt<=15, expcnt/lgkmcnt = no wait
#define WAIT_VM0  0x0F70     // vmcnt<=0

__device__ static inline void load_lds16(const float* g, float* l) {
    __builtin_amdgcn_global_load_lds(
        (const __attribute__((address_space(1))) void*)g,
        (__attribute__((address_space(3))) void*)l,
        16, 0, 0);
}

// 15 global_load_lds instructions per tile (8 pred + 7 target)
__device__ static inline void stage_tile(const float* __restrict__ pred,
                                         const float* __restrict__ target,
                                         int tile, float* sp, float* st, int lane)
{
    const float* gp = pred   + (size_t)tile * 1920;   // 64 cells * 30
    const float* gt = target + (size_t)tile * 1600;   // 64 cells * 25
    #pragma unroll
    for (int r = 0; r < 7; ++r)
        load_lds16(gp + r * 256 + lane * 4, sp + r * 256);
    if (lane < 32)
        load_lds16(gp + 7 * 256 + lane * 4, sp + 7 * 256);
    #pragma unroll
    for (int r = 0; r < 6; ++r)
        load_lds16(gt + r * 256 + lane * 4, st + r * 256);
    if (lane < 16)
        load_lds16(gt + 6 * 256 + lane * 4, st + 6 * 256);
}

__device__ static inline float compute_cell(const float* lp, const float* lt)
{
    const float EPS = 1e-6f;

    const float tobj = lt[20];
    const float tx = lt[21], ty = lt[22], tw = lt[23], th = lt[24];

    const float t_x1 = tx - tw * 0.5f, t_x2 = tx + tw * 0.5f;
    const float t_y1 = ty - th * 0.5f, t_y2 = ty + th * 0.5f;
    const float t_area = fabsf((t_x2 - t_x1) * (t_y2 - t_y1));

    float iou[2];
    #pragma unroll
    for (int b = 0; b < 2; ++b) {
        const float bx = lp[NCLS + 5 * b + 1];
        const float by = lp[NCLS + 5 * b + 2];
        const float bw = lp[NCLS + 5 * b + 3];
        const float bh = lp[NCLS + 5 * b + 4];
        const float x1 = bx - bw * 0.5f, x2 = bx + bw * 0.5f;
        const float y1 = by - bh * 0.5f, y2 = by + bh * 0.5f;
        const float iw = fmaxf(fminf(x2, t_x2) - fmaxf(x1, t_x1), 0.0f);
        const float ih = fmaxf(fminf(y2, t_y2) - fmaxf(y1, t_y1), 0.0f);
        const float inter = iw * ih;
        const float a1 = fabsf((x2 - x1) * (y2 - y1));
        iou[b] = inter / (a1 + t_area - inter + EPS);
    }
    const int best = (iou[1] > iou[0]) ? 1 : 0;

    const float bconf = lp[NCLS + 5 * best + 0];
    const float bxv   = lp[NCLS + 5 * best + 1];
    const float byv   = lp[NCLS + 5 * best + 2];
    const float bwv   = lp[NCLS + 5 * best + 3];
    const float bhv   = lp[NCLS + 5 * best + 4];

    const float sgnw = (bwv > 0.f) ? 1.f : ((bwv < 0.f) ? -1.f : 0.f);
    const float sgnh = (bhv > 0.f) ? 1.f : ((bhv < 0.f) ? -1.f : 0.f);
    const float swv = sgnw * sqrtf(fabsf(bwv) + EPS);
    const float shv = sgnh * sqrtf(fabsf(bhv) + EPS);

    float d0 = tobj * bxv - tobj * tx;
    float d1 = tobj * byv - tobj * ty;
    float d2 = tobj * swv - sqrtf(fmaxf(tobj * tw, 0.0f));
    float d3 = tobj * shv - sqrtf(fmaxf(tobj * th, 0.0f));
    float box_loss = d0 * d0 + d1 * d1 + d2 * d2 + d3 * d3;

    const float noobj = 1.0f - tobj;
    float n0 = noobj * (lp[NCLS + 0] - tobj);
    float n1 = noobj * (lp[NCLS + 5] - tobj);
    float no_object_loss = n0 * n0 + n1 * n1;

    float od = tobj * (bconf - tobj);
    float object_loss = od * od;

    float class_loss = 0.0f;
    #pragma unroll
    for (int k = 0; k < NCLS; ++k) {
        float cd = tobj * (lp[k] - lt[k]);
        class_loss += cd * cd;
    }

    return 5.0f * box_loss + object_loss + 0.5f * no_object_loss + class_loss;
}

__global__ __launch_bounds__(64) void yolo_main(
    const float* __restrict__ pred,
    const float* __restrict__ target,
    float* __restrict__ ws)
{
    __shared__ float sp[2][64 * 30];  // 2 x 7680 B
    __shared__ float st[2][64 * 25];  // 2 x 6400 B

    const int lane = threadIdx.x;
    const int blk  = blockIdx.x;

    const int n = (TILES - blk + GRID - 1) / GRID;   // tiles for this block (>=9)

    stage_tile(pred, target, blk, sp[0], st[0], lane);

    float acc = 0.0f;
    for (int i = 0; i < n; ++i) {
        if (i + 1 < n) {
            stage_tile(pred, target, blk + (i + 1) * GRID,
                       sp[(i + 1) & 1], st[(i + 1) & 1], lane);
            __builtin_amdgcn_s_waitcnt(WAIT_VM15);   // tile i done; i+1 in flight
        } else {
            __builtin_amdgcn_s_waitcnt(WAIT_VM0);    // last tile: full drain
        }
        __asm__ volatile("" ::: "memory");

        const float* lp = sp[i & 1] + lane * 30;
        const float* lt = st[i & 1] + lane * 25;
        acc += compute_cell(lp, lt);

        __asm__ volatile("" ::: "memory");           // keep LDS reads in-iter
    }

    // wave reduce + one atomic per wave into a spread slot
    #pragma unroll
    for (int off = 32; off > 0; off >>= 1)
        acc += __shfl_down(acc, off, 64);

    if (lane == 0)
        atomicAdd(&ws[blk & (SLOTS - 1)], acc);
}

__global__ __launch_bounds__(64) void yolo_reduce(
    const float* __restrict__ ws, float* __restrict__ out)
{
    const int lane = threadIdx.x;
    float s = ws[lane] + ws[lane + 64];
    #pragma unroll
    for (int off = 32; off > 0; off >>= 1)
        s += __shfl_down(s, off, 64);
    if (lane == 0) out[0] = s;
}

extern "C" void kernel_launch(void* const* d_in, const int* in_sizes, int n_in,
                              void* d_out, int out_size, void* d_ws, size_t ws_size,
                              hipStream_t stream) {
    const float* pred   = (const float*)d_in[0];
    const float* target = (const float*)d_in[1];
    float* ws  = (float*)d_ws;
    float* out = (float*)d_out;

    hipMemsetAsync(ws, 0, SLOTS * sizeof(float), stream);

    hipLaunchKernelGGL(yolo_main, dim3(GRID), dim3(64), 0, stream,
                       pred, target, ws);
    hipLaunchKernelGGL(yolo_reduce, dim3(1), dim3(64), 0, stream, ws, out);
}